// Round 13
// baseline (196.177 us; speedup 1.0000x reference)
//
#include <hip/hip_runtime.h>
#include <math.h>

// Problem constants
#define BB  2
#define SS  2048
#define DD  1024
#define HH  16
#define DKK 64

constexpr float kScale = 0.125f;  // 1/sqrt(64)
// p = exp(s*kScale - 16) = 2^(s*C1 - C2); exp(-16) cancels in O = sum(p*v)/sum(p)
constexpr float kC1 = 0.18033688011112042f;  // kScale * log2(e)
constexpr float kC2 = 23.0831206542234144f;  // 16 * log2(e)

typedef __bf16 bf16x8 __attribute__((ext_vector_type(8)));
typedef __bf16 bf16x4 __attribute__((ext_vector_type(4)));
typedef float f32x4 __attribute__((ext_vector_type(4)));

// Async global->LDS, 16 B per lane. LDS dest must be WAVE-UNIFORM base;
// HW scatters lane i to base + i*16.
__device__ __forceinline__ void async_copy16(const void* g, void* l) {
  __builtin_amdgcn_global_load_lds(
      (const __attribute__((address_space(1))) void*)g,
      (__attribute__((address_space(3))) void*)l, 16, 0, 0);
}

// ---------------------------------------------------------------------------
// Fused prep: blocks [0,2048) x->bf16 cvt; [2048,2560) RoPE table;
// [2560,3584) weight transpose+cvt (4 mats x 256 tile-blocks).
// ---------------------------------------------------------------------------
__global__ __launch_bounds__(256) void prep_kernel(
    const float* __restrict__ x, const int* __restrict__ pos,
    const float* __restrict__ W0, const float* __restrict__ W1,
    const float* __restrict__ W2, const float* __restrict__ W3,
    __bf16* __restrict__ xb, float2* __restrict__ rtab,
    __bf16* __restrict__ T0, __bf16* __restrict__ T1,
    __bf16* __restrict__ T2, __bf16* __restrict__ T3) {
  __shared__ __bf16 tile[64][65];
  const int bid = blockIdx.x;
  const int t = threadIdx.x;
  if (bid < 2048) {
    const size_t i = ((size_t)bid * 256 + t) * 8;
    const float4 v0 = *(const float4*)(x + i);
    const float4 v1 = *(const float4*)(x + i + 4);
    bf16x8 o;
    o[0] = (__bf16)v0.x; o[1] = (__bf16)v0.y; o[2] = (__bf16)v0.z; o[3] = (__bf16)v0.w;
    o[4] = (__bf16)v1.x; o[5] = (__bf16)v1.y; o[6] = (__bf16)v1.z; o[7] = (__bf16)v1.w;
    *(bf16x8*)(xb + i) = o;
  } else if (bid < 2560) {
    const int idx = (bid - 2048) * 256 + t;  // 131072 = 4096*32
    const int m = idx >> 5, pi = idx & 31;
    const float inv = exp2f(-0.4152410118609203f * (float)pi);
    float sn, cs;
    __sincosf((float)pos[m] * inv, &sn, &cs);
    rtab[idx] = make_float2(cs, sn);
  } else {
    const int tid2 = bid - 2560;
    const int z = tid2 >> 8, rem = tid2 & 255;
    const float* W;
    __bf16* T;
    switch (z) {
      case 0: W = W0; T = T0; break;
      case 1: W = W1; T = T1; break;
      case 2: W = W2; T = T2; break;
      default: W = W3; T = T3; break;
    }
    const int k0 = (rem >> 4) * 64, n0 = (rem & 15) * 64;
    const int c = t & 63, rg = t >> 6;
#pragma unroll
    for (int i = 0; i < 16; i++) {
      const int r = rg + i * 4;
      tile[r][c] = (__bf16)W[(size_t)(k0 + r) * DD + n0 + c];
    }
    __syncthreads();
#pragma unroll
    for (int i = 0; i < 16; i++) {
      const int r = rg + i * 4;
      T[(size_t)(n0 + r) * DD + k0 + c] = tile[c][r];
    }
  }
}

// ---------------------------------------------------------------------------
// R11 GEMM core: BK=32, TRIPLE-BUFFERED LDS (48 KB total, 3 blocks/CU),
// counted s_waitcnt vmcnt(4) + raw s_barrier (NO vmcnt(0) drain in the main
// loop -- T4). Depth-2 pipeline: tile kt's loads issued in iter kt-2,
// waited at top of iter kt. Race-free: every wave's MFMAs consume its
// ds_reads before barrier(k), so after barrier(k) all reads of buf[(k-1)%3]
// are done and stage(k+2) may overwrite it; vmcnt retires in issue order.
// LDS layout per buffer: [128 rows][4 chunks of 8 bf16]; read slot for
// k-chunk q at row r is q ^ ((r>>1)&3) -> 2 lanes/bank (free). Stage pulls
// the inverse-permuted global chunk into the linear lane-scatter slot.
// C[128,128] += A[128,K] @ Bt[128,K]^T  (K = DD = 1024, 32 steps)
// ---------------------------------------------------------------------------
__device__ __forceinline__ void gemm_core(
    const __bf16* __restrict__ A, const __bf16* __restrict__ Bt,
    int bm, int bn, f32x4 (&acc)[4][4], __bf16* As, __bf16* Bs) {
  const int t = threadIdx.x;
  const int lane = t & 63, wave = t >> 6;
  const int col = lane & 15, quad = lane >> 4;
  const int wm = (wave & 1) * 64, wn = (wave >> 1) * 64;

  // Stage-side: lane -> (row offset r16 = lane>>2, slot = lane&3).
  // Global chunk feeding linear slot s at row r: s ^ ((r16>>1)&3).
  const int r16 = lane >> 2;
  const int gch = (lane & 3) ^ ((r16 >> 1) & 3);
  const __bf16* ag = A + (size_t)(bm + wave * 32 + r16) * DD + gch * 8;
  const __bf16* bg = Bt + (size_t)(bn + wave * 32 + r16) * DD + gch * 8;
  __bf16* asb = As + wave * 1024;  // rows wave*32..+31, 32 elems/row
  __bf16* bsb = Bs + wave * 1024;

  // Read-side swizzled chunk: (row>>1)&3 == (col>>1)&3 for our rows.
  const int rch = (quad ^ ((col >> 1) & 3)) * 8;

  auto stage = [&](int kt, int buf) {
    const int bo = buf * 4096;  // 128 rows * 32 elems per buffer
    async_copy16(ag + kt, asb + bo);                          // rows +0..15
    async_copy16(ag + (size_t)16 * DD + kt, asb + bo + 512);  // rows +16..31
    async_copy16(bg + kt, bsb + bo);
    async_copy16(bg + (size_t)16 * DD + kt, bsb + bo + 512);
  };

  // Prologue: issue tiles 0 and 1 (8 loads in flight).
  stage(0, 0);
  stage(32, 1);

  int rb = 0, sb = 2;  // read buffer, stage buffer (rotating mod 3)
#pragma unroll 1
  for (int step = 0; step < 32; step++) {
    // Wait only the OLDEST tile (kt): keep tile kt+1's 4 loads in flight.
    if (step < 31)
      asm volatile("s_waitcnt vmcnt(4)" ::: "memory");
    else
      asm volatile("s_waitcnt vmcnt(0)" ::: "memory");
    __builtin_amdgcn_s_barrier();      // raw barrier: NO vmcnt drain
    asm volatile("" ::: "memory");     // pin ds_reads below the barrier

    const int bo = rb * 4096;
    bf16x8 af[4], bf[4];
#pragma unroll
    for (int i = 0; i < 4; i++)
      af[i] = *(const bf16x8*)(As + bo + (wm + i * 16 + col) * 32 + rch);
#pragma unroll
    for (int j = 0; j < 4; j++)
      bf[j] = *(const bf16x8*)(Bs + bo + (wn + j * 16 + col) * 32 + rch);

    // Issue tile step+2 into the buffer read in iter step-1 (safe: see top).
    if (step + 2 < 32) stage((step + 2) * 32, sb);

    __builtin_amdgcn_s_setprio(1);
#pragma unroll
    for (int i = 0; i < 4; i++)
#pragma unroll
      for (int j = 0; j < 4; j++)
        acc[i][j] =
            __builtin_amdgcn_mfma_f32_16x16x32_bf16(af[i], bf[j], acc[i][j], 0, 0, 0);
    __builtin_amdgcn_s_setprio(0);

    rb = rb == 2 ? 0 : rb + 1;
    sb = sb == 2 ? 0 : sb + 1;
  }
}

// ---------------------------------------------------------------------------
// R18 narrow GEMM core: C[128,64] += A[128,K] @ Bt[64,K]^T. Same R11
// schedule, 64-wide B tile: 3 stage calls/step -> vmcnt(3); wave grid
// 2M x 2N; acc[4][2], 8 MFMA + 6 ds_read/step. LDS 36 KB.
// ---------------------------------------------------------------------------
__device__ __forceinline__ void gemm_core_n64(
    const __bf16* __restrict__ A, const __bf16* __restrict__ Bt,
    int bm, int bn, f32x4 (&acc)[4][2], __bf16* As, __bf16* Bs) {
  const int t = threadIdx.x;
  const int lane = t & 63, wave = t >> 6;
  const int col = lane & 15, quad = lane >> 4;
  const int wm = (wave & 1) * 64, wn = (wave >> 1) * 32;

  const int r16 = lane >> 2;
  const int gch = (lane & 3) ^ ((r16 >> 1) & 3);
  const __bf16* ag = A + (size_t)(bm + wave * 32 + r16) * DD + gch * 8;
  const __bf16* bg = Bt + (size_t)(bn + wave * 16 + r16) * DD + gch * 8;
  __bf16* asb = As + wave * 1024;  // A rows wave*32..+31
  __bf16* bsb = Bs + wave * 512;   // B rows wave*16..+15

  const int rch = (quad ^ ((col >> 1) & 3)) * 8;

  auto stage = [&](int kt, int buf) {
    async_copy16(ag + kt, asb + buf * 4096);
    async_copy16(ag + (size_t)16 * DD + kt, asb + buf * 4096 + 512);
    async_copy16(bg + kt, bsb + buf * 2048);
  };

  stage(0, 0);
  stage(32, 1);

  int rb = 0, sb = 2;
#pragma unroll 1
  for (int step = 0; step < 32; step++) {
    if (step < 31)
      asm volatile("s_waitcnt vmcnt(3)" ::: "memory");
    else
      asm volatile("s_waitcnt vmcnt(0)" ::: "memory");
    __builtin_amdgcn_s_barrier();
    asm volatile("" ::: "memory");

    bf16x8 af[4], bf[2];
#pragma unroll
    for (int i = 0; i < 4; i++)
      af[i] = *(const bf16x8*)(As + rb * 4096 + (wm + i * 16 + col) * 32 + rch);
#pragma unroll
    for (int j = 0; j < 2; j++)
      bf[j] = *(const bf16x8*)(Bs + rb * 2048 + (wn + j * 16 + col) * 32 + rch);

    if (step + 2 < 32) stage((step + 2) * 32, sb);

    __builtin_amdgcn_s_setprio(1);
#pragma unroll
    for (int i = 0; i < 4; i++)
#pragma unroll
      for (int j = 0; j < 2; j++)
        acc[i][j] =
            __builtin_amdgcn_mfma_f32_16x16x32_bf16(af[i], bf[j], acc[i][j], 0, 0, 0);
    __builtin_amdgcn_s_setprio(0);

    rb = rb == 2 ? 0 : rb + 1;
    sb = sb == 2 ? 0 : sb + 1;
  }
}

// ---------------------------------------------------------------------------
// Fused Q/K/V projection. grid (24, 32): blockIdx.x = mat*8 + n-tile.
// Q,K: RoPE via table, scatter [B,H,S,DK].
// V: operand-swapped MFMA (C^T = Wv^T x^T) -> written DIRECTLY in [B,H,DK,S].
// ---------------------------------------------------------------------------
__global__ __launch_bounds__(256, 3) void qkv_gemm_kernel(
    const __bf16* __restrict__ xb, const __bf16* __restrict__ WqT,
    const __bf16* __restrict__ WkT, const __bf16* __restrict__ WvT,
    const float* __restrict__ bq, const float* __restrict__ bk,
    const float* __restrict__ bv, const float2* __restrict__ ropetab,
    __bf16* __restrict__ qo, __bf16* __restrict__ ko, __bf16* __restrict__ vo) {
  __shared__ __bf16 As[3 * 128 * 32];
  __shared__ __bf16 Bs[3 * 128 * 32];
  const int mat = blockIdx.x >> 3;
  const int bn = (blockIdx.x & 7) * 128;
  const int bm = blockIdx.y * 128;

  f32x4 acc[4][4] = {};
  const int t = threadIdx.x, lane = t & 63, wave = t >> 6;
  const int col = lane & 15, quad = lane >> 4;
  const int wm = (wave & 1) * 64, wn = (wave >> 1) * 64;

  if (mat == 2) {
    // A-operand = WvT rows (n-dim), B-operand = xb rows (m-dim)
    gemm_core(WvT, xb, bn, bm, acc, As, Bs);
    // acc[i][j][r] = Vt[n = bn+wm+i*16+quad*4+r][m = bm+wn+j*16+col]
    const int b = bm >> 11;
#pragma unroll
    for (int i = 0; i < 4; i++) {
#pragma unroll
      for (int r = 0; r < 4; r++) {
        const int n = bn + wm + i * 16 + quad * 4 + r;
        const float bb = bv[n];
        const int h = n >> 6, dk = n & 63;
        __bf16* vrow = vo + ((size_t)(b * HH + h) * DKK + dk) * SS;
#pragma unroll
        for (int j = 0; j < 4; j++) {
          const int m = bm + wn + j * 16 + col;
          vrow[m & (SS - 1)] = (__bf16)(acc[i][j][r] + bb);
        }
      }
    }
    return;
  }

  const __bf16* Bt = mat == 0 ? WqT : WkT;
  const float* bias = mat == 0 ? bq : bk;
  __bf16* out = mat == 0 ? qo : ko;
  gemm_core(xb, Bt, bm, bn, acc, As, Bs);

#pragma unroll
  for (int i = 0; i < 4; i++) {
#pragma unroll
    for (int j = 0; j < 4; j++) {
      const int n = bn + wn + j * 16 + col;
      const float bb = bias[n];
      const int pi = (n & 63) >> 1;
#pragma unroll
      for (int r = 0; r < 4; r++) {
        const int m = bm + wm + i * 16 + quad * 4 + r;
        float v = acc[i][j][r] + bb;
        {
          const float other = __shfl_xor(v, 1, 64);
          const float2 cssn = ropetab[(size_t)m * 32 + pi];
          v = (n & 1) ? (other * cssn.y + v * cssn.x)
                      : (v * cssn.x - other * cssn.y);
        }
        const int h = n >> 6, dk = n & 63;
        const int b = m >> 11, s = m & (SS - 1);
        out[((size_t)(b * HH + h) * SS + s) * DKK + dk] = (__bf16)v;
      }
    }
  }
}

// ---------------------------------------------------------------------------
// O projection: 128x64 tiles, grid (16, 32) = 512 blocks = 2/CU.
// out[M,N] fp32 = ob[M,K] @ WoT[N,K]^T + bo.
// ---------------------------------------------------------------------------
__global__ __launch_bounds__(256, 4) void oproj_gemm_kernel(
    const __bf16* __restrict__ ob, const __bf16* __restrict__ WoT,
    const float* __restrict__ bo, float* __restrict__ out) {
  __shared__ __bf16 As[3 * 128 * 32];
  __shared__ __bf16 Bs[3 * 64 * 32];
  const int bn = blockIdx.x * 64;
  const int bm = blockIdx.y * 128;
  f32x4 acc[4][2] = {};
  gemm_core_n64(ob, WoT, bm, bn, acc, As, Bs);

  const int t = threadIdx.x, lane = t & 63, wave = t >> 6;
  const int col = lane & 15, quad = lane >> 4;
  const int wm = (wave & 1) * 64, wn = (wave >> 1) * 32;
#pragma unroll
  for (int i = 0; i < 4; i++) {
#pragma unroll
    for (int j = 0; j < 2; j++) {
      const int n = bn + wn + j * 16 + col;
      const float bb = bo[n];
#pragma unroll
      for (int r = 0; r < 4; r++) {
        const int m = bm + wm + i * 16 + quad * 4 + r;
        out[(size_t)m * DD + n] = acc[i][j][r] + bb;
      }
    }
  }
}

// ---------------------------------------------------------------------------
// MFMA flash attention, R19: split-KV extended to nSplit qtiles (max-cost
// balance). With nSplit=8 (ws >= 51 MB; WoT relocated): qt 8..15 split in
// halves (cost 9..16), qt 0..7 whole (cost 2..16) -> grid (32,24) = 768
// blocks = EXACTLY 3/CU, max block cost 16 (was 18) -> utilization
// 63% -> 71%. Fallback nSplit=7 == proven R12 (191 us).
// Fixed-max softmax => partials ADDITIVE: split halves write unnormalized
// fp32 O + per-row l; combine kernel divides. p = 2^(s*C1 - C2).
// q,k in [B,H,S,DK]; vt in [B,H,DK,S]; o out [B,S,H,DK] bf16.
// ---------------------------------------------------------------------------
__global__ __launch_bounds__(512, 6) void flash_attn_mfma_kernel(
    const __bf16* __restrict__ q, const __bf16* __restrict__ k,
    const __bf16* __restrict__ vt, __bf16* __restrict__ o,
    float* __restrict__ Opart, float* __restrict__ lpart, int nSplit) {
  __shared__ __bf16 Ks[2][64 * 64];    // [buf][j][dk], chunk-swizzled
  __shared__ __bf16 Vs[2][64 * 64];    // [buf][d][j],  chunk-swizzled
  __shared__ __bf16 Ps[8][16 * 72];    // per-wave [qrow][j], stride 72

  const int bh = blockIdx.x;            // 0..31
  const int y = blockIdx.y;             // 0..(16+nSplit-1)
  int qtile, ktBeg, ktEnd, half;
  bool isSplit;
  if (y < 2 * nSplit) {
    qtile = 15 - (y >> 1);
    half = y & 1;
    isSplit = true;
    ktBeg = half ? (qtile + 1) : 0;
    ktEnd = half ? (2 * qtile + 2) : (qtile + 1);
  } else {
    qtile = (15 - nSplit) - (y - 2 * nSplit);  // (15-nSplit)..0
    half = 0;
    isSplit = false;
    ktBeg = 0;
    ktEnd = 2 * qtile + 2;
  }

  const int t = threadIdx.x, lane = t & 63, wave = t >> 6;  // wave 0..7
  const int col = lane & 15, quad = lane >> 4;
  const int r8 = lane >> 3;             // row in 8-row slab
  const int cg = (lane & 7) ^ r8;       // swizzled global chunk
  const int w4 = wave & 3;              // 16-row group within 64-row half

  const __bf16* qb = q + (size_t)bh * SS * DKK;
  const __bf16* kb = k + (size_t)bh * SS * DKK;
  const __bf16* vtb = vt + (size_t)bh * DKK * SS;
  const int b = bh / HH, h = bh % HH;
  __bf16* pw = (__bf16*)Ps[wave];

  const int rbase = qtile * 128 + wave * 16;  // this wave's 16 q-rows
  const int myDiag = 2 * qtile + (wave >> 2); // K-tile straddling my rows

  // Q fragments held in registers (B-operand of swapped QK^T: lane col holds
  // q-row rbase+col, k-elems ks*32+quad*8..+7)
  bf16x8 qf[2];
#pragma unroll
  for (int ks = 0; ks < 2; ks++)
    qf[ks] = *(const bf16x8*)(qb + (size_t)(rbase + col) * DKK + ks * 32 +
                              quad * 8);

  f32x4 oacc[4] = {};
  float l_lane = 0.f;

  // Stage K/V tile kt into buffer buf; wave w covers slab w (8 rows each).
  auto stage = [&](int kt, int buf) {
    async_copy16(kb + (size_t)(kt * 64 + wave * 8 + r8) * DKK + cg * 8,
                 &Ks[buf][wave * 512]);
    async_copy16(vtb + (size_t)(wave * 8 + r8) * SS + kt * 64 + cg * 8,
                 &Vs[buf][wave * 512]);
  };

  // Prologue: stage first tile, drain, barrier.
  stage(ktBeg, 0);
  __syncthreads();

  int cur = 0;
  for (int kt = ktBeg; kt < ktEnd; kt++) {
    // Issue next tile's loads FIRST -> latency hides under this tile's
    // compute; the single end-of-iteration barrier drains them.
    if (kt + 1 < ktEnd) stage(kt + 1, cur ^ 1);

    if (kt <= myDiag) {
      // ---- swapped QK^T: sc[ct][r] = S[token = kt*64+ct*16+quad*4+r]
      //                                 [qrow  = rbase + col] ----
      f32x4 sc[4] = {};
      __builtin_amdgcn_s_setprio(1);
#pragma unroll
      for (int ct = 0; ct < 4; ct++)
#pragma unroll
        for (int ks = 0; ks < 2; ks++) {
          const bf16x8 kf = *(const bf16x8*)(&Ks[cur][(ct * 16 + col) * 64 +
                                             (((ks * 4 + quad) ^ (col & 7)) * 8)]);
          sc[ct] = __builtin_amdgcn_mfma_f32_16x16x32_bf16(kf, qf[ks], sc[ct],
                                                           0, 0, 0);
        }
      __builtin_amdgcn_s_setprio(0);

      // ---- softmax: p = 2^(s*C1 - C2); packed b64 store to Ps[qrow][token],
      // token = ct*16 + quad*4 + r, qrow = col. Mask only on diag tile. ----
      if (kt < myDiag) {
#pragma unroll
        for (int ct = 0; ct < 4; ct++) {
          float p0 = exp2f(sc[ct][0] * kC1 - kC2);
          float p1 = exp2f(sc[ct][1] * kC1 - kC2);
          float p2 = exp2f(sc[ct][2] * kC1 - kC2);
          float p3 = exp2f(sc[ct][3] * kC1 - kC2);
          l_lane += (p0 + p1) + (p2 + p3);
          bf16x4 pv;
          pv[0] = (__bf16)p0; pv[1] = (__bf16)p1;
          pv[2] = (__bf16)p2; pv[3] = (__bf16)p3;
          *(bf16x4*)(pw + col * 72 + ct * 16 + quad * 4) = pv;
        }
      } else {
        // diag tile: token-local (ct*16+quad*4+r) vs qrow-local (w4*16+col)
#pragma unroll
        for (int ct = 0; ct < 4; ct++) {
          bf16x4 pv;
          if (ct > w4) {  // whole 16-token block above the diagonal
            pv[0] = pv[1] = pv[2] = pv[3] = (__bf16)0.0f;
          } else if (ct < w4) {  // fully below: no mask
            float p0 = exp2f(sc[ct][0] * kC1 - kC2);
            float p1 = exp2f(sc[ct][1] * kC1 - kC2);
            float p2 = exp2f(sc[ct][2] * kC1 - kC2);
            float p3 = exp2f(sc[ct][3] * kC1 - kC2);
            l_lane += (p0 + p1) + (p2 + p3);
            pv[0] = (__bf16)p0; pv[1] = (__bf16)p1;
            pv[2] = (__bf16)p2; pv[3] = (__bf16)p3;
          } else {  // ct == w4: per-element mask
#pragma unroll
            for (int r = 0; r < 4; r++) {
              float p = exp2f(sc[ct][r] * kC1 - kC2);
              if (quad * 4 + r > col) p = 0.0f;
              l_lane += p;
              pv[r] = (__bf16)p;
            }
          }
          *(bf16x4*)(pw + col * 72 + ct * 16 + quad * 4) = pv;
        }
      }

      // ---- PV: O[qrow][dt*16+col] += P @ Vt^T (wave-private P) ----
      {
        bf16x8 pf[2];
#pragma unroll
        for (int ks = 0; ks < 2; ks++)
          pf[ks] = *(const bf16x8*)(pw + col * 72 + ks * 32 + quad * 8);
        __builtin_amdgcn_s_setprio(1);
#pragma unroll
        for (int dt = 0; dt < 4; dt++)
#pragma unroll
          for (int ks = 0; ks < 2; ks++) {
            const bf16x8 vf = *(const bf16x8*)(&Vs[cur][(dt * 16 + col) * 64 +
                                               (((ks * 4 + quad) ^ (col & 7)) * 8)]);
            oacc[dt] = __builtin_amdgcn_mfma_f32_16x16x32_bf16(pf[ks], vf,
                                                               oacc[dt], 0, 0, 0);
          }
        __builtin_amdgcn_s_setprio(0);
      }
    }

    // One barrier per tile: waits this tile's readers AND next tile's
    // prefetch (already overlapped with the compute above).
    __syncthreads();
    cur ^= 1;
  }

  // Reduce l over quads: after these, every lane holds l[qrow = col].
  float l = l_lane;
  l += __shfl_xor(l, 16, 64);
  l += __shfl_xor(l, 32, 64);

  if (!isSplit) {
    // Whole qtile: normalize and write o directly.
#pragma unroll
    for (int r = 0; r < 4; r++) {
      const float lr = __shfl(l, quad * 4 + r, 64);
      const float inv_l = 1.0f / lr;
      const int s = rbase + quad * 4 + r;
#pragma unroll
      for (int dt = 0; dt < 4; dt++)
        o[((size_t)(b * SS + s) * HH + h) * DKK + dt * 16 + col] =
            (__bf16)(oacc[dt][r] * inv_l);
    }
  } else {
    // Split half: dump unnormalized fp32 O + per-row l; combine divides.
    const int tile = (bh * nSplit + (qtile - (16 - nSplit))) * 2 + half;
    float* Op = Opart + (size_t)tile * (128 * 64);
#pragma unroll
    for (int r = 0; r < 4; r++) {
      const int row = wave * 16 + quad * 4 + r;
#pragma unroll
      for (int dt = 0; dt < 4; dt++)
        Op[row * 64 + dt * 16 + col] = oacc[dt][r];
    }
    if (quad == 0) lpart[tile * 128 + wave * 16 + col] = l;
  }
}

// ---------------------------------------------------------------------------
// Combine split-KV partials: o = (Oa + Ob) / (la + lb), write bf16.
// grid 32*nSplit; 256 threads: 2 threads per row.
// ---------------------------------------------------------------------------
__global__ __launch_bounds__(256) void combine_kernel(
    const float* __restrict__ Opart, const float* __restrict__ lpart,
    __bf16* __restrict__ o, int nSplit) {
  const int bh = blockIdx.x / nSplit, qi = blockIdx.x % nSplit;
  const int qtile = qi + (16 - nSplit);
  const int b = bh / HH, h = bh % HH;
  const int t = threadIdx.x;
  const int row = t >> 1, dk0 = (t & 1) * 32;
  const int ta = (bh * nSplit + qi) * 2, tb = ta + 1;
  const float la = lpart[ta * 128 + row], lb = lpart[tb * 128 + row];
  const float inv = 1.0f / (la + lb);
  const int s = qtile * 128 + row;
  const float* Oa = Opart + (size_t)ta * 8192 + row * 64 + dk0;
  const float* Ob = Opart + (size_t)tb * 8192 + row * 64 + dk0;
  __bf16* orow = o + ((size_t)(b * SS + s) * HH + h) * DKK + dk0;
#pragma unroll
  for (int i = 0; i < 32; i += 4) {
    const float4 a = *(const float4*)(Oa + i);
    const float4 bb = *(const float4*)(Ob + i);
    orow[i + 0] = (__bf16)((a.x + bb.x) * inv);
    orow[i + 1] = (__bf16)((a.y + bb.y) * inv);
    orow[i + 2] = (__bf16)((a.z + bb.z) * inv);
    orow[i + 3] = (__bf16)((a.w + bb.w) * inv);
  }
}

// ---------------------------------------------------------------------------
extern "C" void kernel_launch(void* const* d_in, const int* in_sizes, int n_in,
                              void* d_out, int out_size, void* d_ws,
                              size_t ws_size, hipStream_t stream) {
  const float* x  = (const float*)d_in[0];
  const int*  pos = (const int*)d_in[1];
  const float* Wq = (const float*)d_in[2];
  const float* bq = (const float*)d_in[3];
  const float* Wk = (const float*)d_in[4];
  const float* bk = (const float*)d_in[5];
  const float* Wv = (const float*)d_in[6];
  const float* bv = (const float*)d_in[7];
  const float* Wo = (const float*)d_in[8];
  const float* bo = (const float*)d_in[9];
  float* out = (float*)d_out;

  char* ws = (char*)d_ws;
  __bf16* xb  = (__bf16*)(ws);                          // 8 MB (dead after qkv)
  __bf16* WqT = (__bf16*)(ws + ((size_t)8  << 20));     // 2 MB each
  __bf16* WkT = (__bf16*)(ws + ((size_t)10 << 20));
  __bf16* WvT = (__bf16*)(ws + ((size_t)12 << 20));
  __bf16* qb  = (__bf16*)(ws + ((size_t)16 << 20));     // 8 MB each
  __bf16* kb  = (__bf16*)(ws + ((size_t)24 << 20));
  __bf16* vtb = (__bf16*)(ws + ((size_t)32 << 20));     // V, transposed layout
  __bf16* ob  = (__bf16*)(ws + ((size_t)40 << 20));
  float2* rtab = (float2*)(ws + ((size_t)48 << 20));    // 1 MB

  // nSplit=8 needs Opart = 512x32KB = 16 MB over [0,16) -> WoT must move out
  // of [14,16). Relocate WoT to [49,51) when workspace allows (harness fill
  // shows ws ~ 256 MB); fallback nSplit=7 == proven R12 layout.
  const bool bigWs = ws_size >= ((size_t)51 << 20);
  const int nSplit = bigWs ? 8 : 7;
  __bf16* WoT = (__bf16*)(ws + (bigWs ? ((size_t)49 << 20)
                                      : ((size_t)14 << 20)));
  float* Opart = (float*)(ws);                          // nSplit*64 tiles
  float* lpart = (float*)(ws + ((size_t)48 << 20));     // 256 KB, over rtab

  prep_kernel<<<3584, 256, 0, stream>>>(x, pos, Wq, Wk, Wv, Wo, xb, rtab, WqT,
                                        WkT, WvT, WoT);
  qkv_gemm_kernel<<<dim3(24, 32), 256, 0, stream>>>(xb, WqT, WkT, WvT, bq, bk,
                                                    bv, rtab, qb, kb, vtb);
  flash_attn_mfma_kernel<<<dim3(32, 16 + nSplit), 512, 0, stream>>>(
      qb, kb, vtb, ob, Opart, lpart, nSplit);
  combine_kernel<<<32 * nSplit, 256, 0, stream>>>(Opart, lpart, ob, nSplit);
  oproj_gemm_kernel<<<dim3(16, 32), 256, 0, stream>>>(ob, WoT, bo, out);
}

// Round 14
// 191.361 us; speedup vs baseline: 1.0252x; 1.0252x over previous
//
#include <hip/hip_runtime.h>
#include <math.h>

// Problem constants
#define BB  2
#define SS  2048
#define DD  1024
#define HH  16
#define DKK 64

constexpr float kScale = 0.125f;  // 1/sqrt(64)
// p = exp(s*kScale - 16) = 2^(s*C1 - C2); exp(-16) cancels in O = sum(p*v)/sum(p)
constexpr float kC1 = 0.18033688011112042f;  // kScale * log2(e)
constexpr float kC2 = 23.0831206542234144f;  // 16 * log2(e)

typedef __bf16 bf16x8 __attribute__((ext_vector_type(8)));
typedef __bf16 bf16x4 __attribute__((ext_vector_type(4)));
typedef float f32x4 __attribute__((ext_vector_type(4)));

// Async global->LDS, 16 B per lane. LDS dest must be WAVE-UNIFORM base;
// HW scatters lane i to base + i*16.
__device__ __forceinline__ void async_copy16(const void* g, void* l) {
  __builtin_amdgcn_global_load_lds(
      (const __attribute__((address_space(1))) void*)g,
      (__attribute__((address_space(3))) void*)l, 16, 0, 0);
}

// ---------------------------------------------------------------------------
// Fused prep: blocks [0,2048) x->bf16 cvt; [2048,2560) RoPE table;
// [2560,3584) weight transpose+cvt (4 mats x 256 tile-blocks).
// ---------------------------------------------------------------------------
__global__ __launch_bounds__(256) void prep_kernel(
    const float* __restrict__ x, const int* __restrict__ pos,
    const float* __restrict__ W0, const float* __restrict__ W1,
    const float* __restrict__ W2, const float* __restrict__ W3,
    __bf16* __restrict__ xb, float2* __restrict__ rtab,
    __bf16* __restrict__ T0, __bf16* __restrict__ T1,
    __bf16* __restrict__ T2, __bf16* __restrict__ T3) {
  __shared__ __bf16 tile[64][65];
  const int bid = blockIdx.x;
  const int t = threadIdx.x;
  if (bid < 2048) {
    const size_t i = ((size_t)bid * 256 + t) * 8;
    const float4 v0 = *(const float4*)(x + i);
    const float4 v1 = *(const float4*)(x + i + 4);
    bf16x8 o;
    o[0] = (__bf16)v0.x; o[1] = (__bf16)v0.y; o[2] = (__bf16)v0.z; o[3] = (__bf16)v0.w;
    o[4] = (__bf16)v1.x; o[5] = (__bf16)v1.y; o[6] = (__bf16)v1.z; o[7] = (__bf16)v1.w;
    *(bf16x8*)(xb + i) = o;
  } else if (bid < 2560) {
    const int idx = (bid - 2048) * 256 + t;  // 131072 = 4096*32
    const int m = idx >> 5, pi = idx & 31;
    const float inv = exp2f(-0.4152410118609203f * (float)pi);
    float sn, cs;
    __sincosf((float)pos[m] * inv, &sn, &cs);
    rtab[idx] = make_float2(cs, sn);
  } else {
    const int tid2 = bid - 2560;
    const int z = tid2 >> 8, rem = tid2 & 255;
    const float* W;
    __bf16* T;
    switch (z) {
      case 0: W = W0; T = T0; break;
      case 1: W = W1; T = T1; break;
      case 2: W = W2; T = T2; break;
      default: W = W3; T = T3; break;
    }
    const int k0 = (rem >> 4) * 64, n0 = (rem & 15) * 64;
    const int c = t & 63, rg = t >> 6;
#pragma unroll
    for (int i = 0; i < 16; i++) {
      const int r = rg + i * 4;
      tile[r][c] = (__bf16)W[(size_t)(k0 + r) * DD + n0 + c];
    }
    __syncthreads();
#pragma unroll
    for (int i = 0; i < 16; i++) {
      const int r = rg + i * 4;
      T[(size_t)(n0 + r) * DD + k0 + c] = tile[c][r];
    }
  }
}

// ---------------------------------------------------------------------------
// R11 GEMM core: BK=32, TRIPLE-BUFFERED LDS (48 KB total, 3 blocks/CU),
// counted s_waitcnt vmcnt(4) + raw s_barrier (NO vmcnt(0) drain in the main
// loop -- T4). Depth-2 pipeline: tile kt's loads issued in iter kt-2,
// waited at top of iter kt. Race-free: every wave's MFMAs consume its
// ds_reads before barrier(k), so after barrier(k) all reads of buf[(k-1)%3]
// are done and stage(k+2) may overwrite it; vmcnt retires in issue order.
// LDS layout per buffer: [128 rows][4 chunks of 8 bf16]; read slot for
// k-chunk q at row r is q ^ ((r>>1)&3) -> 2 lanes/bank (free). Stage pulls
// the inverse-permuted global chunk into the linear lane-scatter slot.
// C[128,128] += A[128,K] @ Bt[128,K]^T  (K = DD = 1024, 32 steps)
// ---------------------------------------------------------------------------
__device__ __forceinline__ void gemm_core(
    const __bf16* __restrict__ A, const __bf16* __restrict__ Bt,
    int bm, int bn, f32x4 (&acc)[4][4], __bf16* As, __bf16* Bs) {
  const int t = threadIdx.x;
  const int lane = t & 63, wave = t >> 6;
  const int col = lane & 15, quad = lane >> 4;
  const int wm = (wave & 1) * 64, wn = (wave >> 1) * 64;

  // Stage-side: lane -> (row offset r16 = lane>>2, slot = lane&3).
  // Global chunk feeding linear slot s at row r: s ^ ((r16>>1)&3).
  const int r16 = lane >> 2;
  const int gch = (lane & 3) ^ ((r16 >> 1) & 3);
  const __bf16* ag = A + (size_t)(bm + wave * 32 + r16) * DD + gch * 8;
  const __bf16* bg = Bt + (size_t)(bn + wave * 32 + r16) * DD + gch * 8;
  __bf16* asb = As + wave * 1024;  // rows wave*32..+31, 32 elems/row
  __bf16* bsb = Bs + wave * 1024;

  // Read-side swizzled chunk: (row>>1)&3 == (col>>1)&3 for our rows.
  const int rch = (quad ^ ((col >> 1) & 3)) * 8;

  auto stage = [&](int kt, int buf) {
    const int bo = buf * 4096;  // 128 rows * 32 elems per buffer
    async_copy16(ag + kt, asb + bo);                          // rows +0..15
    async_copy16(ag + (size_t)16 * DD + kt, asb + bo + 512);  // rows +16..31
    async_copy16(bg + kt, bsb + bo);
    async_copy16(bg + (size_t)16 * DD + kt, bsb + bo + 512);
  };

  // Prologue: issue tiles 0 and 1 (8 loads in flight).
  stage(0, 0);
  stage(32, 1);

  int rb = 0, sb = 2;  // read buffer, stage buffer (rotating mod 3)
#pragma unroll 1
  for (int step = 0; step < 32; step++) {
    // Wait only the OLDEST tile (kt): keep tile kt+1's 4 loads in flight.
    if (step < 31)
      asm volatile("s_waitcnt vmcnt(4)" ::: "memory");
    else
      asm volatile("s_waitcnt vmcnt(0)" ::: "memory");
    __builtin_amdgcn_s_barrier();      // raw barrier: NO vmcnt drain
    asm volatile("" ::: "memory");     // pin ds_reads below the barrier

    const int bo = rb * 4096;
    bf16x8 af[4], bf[4];
#pragma unroll
    for (int i = 0; i < 4; i++)
      af[i] = *(const bf16x8*)(As + bo + (wm + i * 16 + col) * 32 + rch);
#pragma unroll
    for (int j = 0; j < 4; j++)
      bf[j] = *(const bf16x8*)(Bs + bo + (wn + j * 16 + col) * 32 + rch);

    // Issue tile step+2 into the buffer read in iter step-1 (safe: see top).
    if (step + 2 < 32) stage((step + 2) * 32, sb);

    __builtin_amdgcn_s_setprio(1);
#pragma unroll
    for (int i = 0; i < 4; i++)
#pragma unroll
      for (int j = 0; j < 4; j++)
        acc[i][j] =
            __builtin_amdgcn_mfma_f32_16x16x32_bf16(af[i], bf[j], acc[i][j], 0, 0, 0);
    __builtin_amdgcn_s_setprio(0);

    rb = rb == 2 ? 0 : rb + 1;
    sb = sb == 2 ? 0 : sb + 1;
  }
}

// ---------------------------------------------------------------------------
// R18 narrow GEMM core: C[128,64] += A[128,K] @ Bt[64,K]^T. Same R11
// schedule, 64-wide B tile: 3 stage calls/step -> vmcnt(3); wave grid
// 2M x 2N; acc[4][2], 8 MFMA + 6 ds_read/step. LDS 36 KB.
// ---------------------------------------------------------------------------
__device__ __forceinline__ void gemm_core_n64(
    const __bf16* __restrict__ A, const __bf16* __restrict__ Bt,
    int bm, int bn, f32x4 (&acc)[4][2], __bf16* As, __bf16* Bs) {
  const int t = threadIdx.x;
  const int lane = t & 63, wave = t >> 6;
  const int col = lane & 15, quad = lane >> 4;
  const int wm = (wave & 1) * 64, wn = (wave >> 1) * 32;

  const int r16 = lane >> 2;
  const int gch = (lane & 3) ^ ((r16 >> 1) & 3);
  const __bf16* ag = A + (size_t)(bm + wave * 32 + r16) * DD + gch * 8;
  const __bf16* bg = Bt + (size_t)(bn + wave * 16 + r16) * DD + gch * 8;
  __bf16* asb = As + wave * 1024;  // A rows wave*32..+31
  __bf16* bsb = Bs + wave * 512;   // B rows wave*16..+15

  const int rch = (quad ^ ((col >> 1) & 3)) * 8;

  auto stage = [&](int kt, int buf) {
    async_copy16(ag + kt, asb + buf * 4096);
    async_copy16(ag + (size_t)16 * DD + kt, asb + buf * 4096 + 512);
    async_copy16(bg + kt, bsb + buf * 2048);
  };

  stage(0, 0);
  stage(32, 1);

  int rb = 0, sb = 2;
#pragma unroll 1
  for (int step = 0; step < 32; step++) {
    if (step < 31)
      asm volatile("s_waitcnt vmcnt(3)" ::: "memory");
    else
      asm volatile("s_waitcnt vmcnt(0)" ::: "memory");
    __builtin_amdgcn_s_barrier();
    asm volatile("" ::: "memory");

    bf16x8 af[4], bf[2];
#pragma unroll
    for (int i = 0; i < 4; i++)
      af[i] = *(const bf16x8*)(As + rb * 4096 + (wm + i * 16 + col) * 32 + rch);
#pragma unroll
    for (int j = 0; j < 2; j++)
      bf[j] = *(const bf16x8*)(Bs + rb * 2048 + (wn + j * 16 + col) * 32 + rch);

    if (step + 2 < 32) stage((step + 2) * 32, sb);

    __builtin_amdgcn_s_setprio(1);
#pragma unroll
    for (int i = 0; i < 4; i++)
#pragma unroll
      for (int j = 0; j < 2; j++)
        acc[i][j] =
            __builtin_amdgcn_mfma_f32_16x16x32_bf16(af[i], bf[j], acc[i][j], 0, 0, 0);
    __builtin_amdgcn_s_setprio(0);

    rb = rb == 2 ? 0 : rb + 1;
    sb = sb == 2 ? 0 : sb + 1;
  }
}

// ---------------------------------------------------------------------------
// Fused Q/K/V projection. grid (24, 32): blockIdx.x = mat*8 + n-tile.
// Q,K: RoPE via table, scatter [B,H,S,DK].
// V: operand-swapped MFMA (C^T = Wv^T x^T) -> written DIRECTLY in [B,H,DK,S].
// ---------------------------------------------------------------------------
__global__ __launch_bounds__(256, 3) void qkv_gemm_kernel(
    const __bf16* __restrict__ xb, const __bf16* __restrict__ WqT,
    const __bf16* __restrict__ WkT, const __bf16* __restrict__ WvT,
    const float* __restrict__ bq, const float* __restrict__ bk,
    const float* __restrict__ bv, const float2* __restrict__ ropetab,
    __bf16* __restrict__ qo, __bf16* __restrict__ ko, __bf16* __restrict__ vo) {
  __shared__ __bf16 As[3 * 128 * 32];
  __shared__ __bf16 Bs[3 * 128 * 32];
  const int mat = blockIdx.x >> 3;
  const int bn = (blockIdx.x & 7) * 128;
  const int bm = blockIdx.y * 128;

  f32x4 acc[4][4] = {};
  const int t = threadIdx.x, lane = t & 63, wave = t >> 6;
  const int col = lane & 15, quad = lane >> 4;
  const int wm = (wave & 1) * 64, wn = (wave >> 1) * 64;

  if (mat == 2) {
    // A-operand = WvT rows (n-dim), B-operand = xb rows (m-dim)
    gemm_core(WvT, xb, bn, bm, acc, As, Bs);
    // acc[i][j][r] = Vt[n = bn+wm+i*16+quad*4+r][m = bm+wn+j*16+col]
    const int b = bm >> 11;
#pragma unroll
    for (int i = 0; i < 4; i++) {
#pragma unroll
      for (int r = 0; r < 4; r++) {
        const int n = bn + wm + i * 16 + quad * 4 + r;
        const float bb = bv[n];
        const int h = n >> 6, dk = n & 63;
        __bf16* vrow = vo + ((size_t)(b * HH + h) * DKK + dk) * SS;
#pragma unroll
        for (int j = 0; j < 4; j++) {
          const int m = bm + wn + j * 16 + col;
          vrow[m & (SS - 1)] = (__bf16)(acc[i][j][r] + bb);
        }
      }
    }
    return;
  }

  const __bf16* Bt = mat == 0 ? WqT : WkT;
  const float* bias = mat == 0 ? bq : bk;
  __bf16* out = mat == 0 ? qo : ko;
  gemm_core(xb, Bt, bm, bn, acc, As, Bs);

#pragma unroll
  for (int i = 0; i < 4; i++) {
#pragma unroll
    for (int j = 0; j < 4; j++) {
      const int n = bn + wn + j * 16 + col;
      const float bb = bias[n];
      const int pi = (n & 63) >> 1;
#pragma unroll
      for (int r = 0; r < 4; r++) {
        const int m = bm + wm + i * 16 + quad * 4 + r;
        float v = acc[i][j][r] + bb;
        {
          const float other = __shfl_xor(v, 1, 64);
          const float2 cssn = ropetab[(size_t)m * 32 + pi];
          v = (n & 1) ? (other * cssn.y + v * cssn.x)
                      : (v * cssn.x - other * cssn.y);
        }
        const int h = n >> 6, dk = n & 63;
        const int b = m >> 11, s = m & (SS - 1);
        out[((size_t)(b * HH + h) * SS + s) * DKK + dk] = (__bf16)v;
      }
    }
  }
}

// ---------------------------------------------------------------------------
// O projection: 128x64 tiles, grid (16, 32) = 512 blocks = 2/CU.
// out[M,N] fp32 = ob[M,K] @ WoT[N,K]^T + bo.
// ---------------------------------------------------------------------------
__global__ __launch_bounds__(256, 4) void oproj_gemm_kernel(
    const __bf16* __restrict__ ob, const __bf16* __restrict__ WoT,
    const float* __restrict__ bo, float* __restrict__ out) {
  __shared__ __bf16 As[3 * 128 * 32];
  __shared__ __bf16 Bs[3 * 64 * 32];
  const int bn = blockIdx.x * 64;
  const int bm = blockIdx.y * 128;
  f32x4 acc[4][2] = {};
  gemm_core_n64(ob, WoT, bm, bn, acc, As, Bs);

  const int t = threadIdx.x, lane = t & 63, wave = t >> 6;
  const int col = lane & 15, quad = lane >> 4;
  const int wm = (wave & 1) * 64, wn = (wave >> 1) * 32;
#pragma unroll
  for (int i = 0; i < 4; i++) {
#pragma unroll
    for (int j = 0; j < 2; j++) {
      const int n = bn + wn + j * 16 + col;
      const float bb = bo[n];
#pragma unroll
      for (int r = 0; r < 4; r++) {
        const int m = bm + wm + i * 16 + quad * 4 + r;
        out[(size_t)m * DD + n] = acc[i][j][r] + bb;
      }
    }
  }
}

// ---------------------------------------------------------------------------
// MFMA flash attention (= R12 exact, proven 44.4-44.9 us flash, 190.7 total
// -- session best). Split-KV: 8-wave 512-thread blocks, 128-row Q-supertile,
// grid (32,23) = 736 blocks co-resident at 3 blocks/CU.
//   y in [0,14): split halves of qtiles 9..15; y in [14,23): whole 8..0.
// Refuted by counters: reg-P (R13/14), fused-combine fences (R9), 32x32
// MFMA (R16), nSplit=8 (R13: max-cost 18->16 but per-iter +20% from extra
// partial traffic + zero-slack contention -- balance model overweights
// idle slots). Fixed-max softmax => partials ADDITIVE: split halves write
// unnormalized fp32 O + per-row l; combine kernel divides. p = 2^(s*C1-C2).
// q,k in [B,H,S,DK]; vt in [B,H,DK,S]; o out [B,S,H,DK] bf16.
// ---------------------------------------------------------------------------
__global__ __launch_bounds__(512, 6) void flash_attn_mfma_kernel(
    const __bf16* __restrict__ q, const __bf16* __restrict__ k,
    const __bf16* __restrict__ vt, __bf16* __restrict__ o,
    float* __restrict__ Opart, float* __restrict__ lpart) {
  __shared__ __bf16 Ks[2][64 * 64];    // [buf][j][dk], chunk-swizzled
  __shared__ __bf16 Vs[2][64 * 64];    // [buf][d][j],  chunk-swizzled
  __shared__ __bf16 Ps[8][16 * 72];    // per-wave [qrow][j], stride 72

  const int bh = blockIdx.x;            // 0..31
  const int y = blockIdx.y;             // 0..22
  int qtile, ktBeg, ktEnd, half;
  bool isSplit;
  if (y < 14) {
    qtile = 15 - (y >> 1);
    half = y & 1;
    isSplit = true;
    ktBeg = half ? (qtile + 1) : 0;
    ktEnd = half ? (2 * qtile + 2) : (qtile + 1);
  } else {
    qtile = 22 - y;                     // 8..0
    half = 0;
    isSplit = false;
    ktBeg = 0;
    ktEnd = 2 * qtile + 2;
  }

  const int t = threadIdx.x, lane = t & 63, wave = t >> 6;  // wave 0..7
  const int col = lane & 15, quad = lane >> 4;
  const int r8 = lane >> 3;             // row in 8-row slab
  const int cg = (lane & 7) ^ r8;       // swizzled global chunk
  const int w4 = wave & 3;              // 16-row group within 64-row half

  const __bf16* qb = q + (size_t)bh * SS * DKK;
  const __bf16* kb = k + (size_t)bh * SS * DKK;
  const __bf16* vtb = vt + (size_t)bh * DKK * SS;
  const int b = bh / HH, h = bh % HH;
  __bf16* pw = (__bf16*)Ps[wave];

  const int rbase = qtile * 128 + wave * 16;  // this wave's 16 q-rows
  const int myDiag = 2 * qtile + (wave >> 2); // K-tile straddling my rows

  // Q fragments held in registers (B-operand of swapped QK^T: lane col holds
  // q-row rbase+col, k-elems ks*32+quad*8..+7)
  bf16x8 qf[2];
#pragma unroll
  for (int ks = 0; ks < 2; ks++)
    qf[ks] = *(const bf16x8*)(qb + (size_t)(rbase + col) * DKK + ks * 32 +
                              quad * 8);

  f32x4 oacc[4] = {};
  float l_lane = 0.f;

  // Stage K/V tile kt into buffer buf; wave w covers slab w (8 rows each).
  auto stage = [&](int kt, int buf) {
    async_copy16(kb + (size_t)(kt * 64 + wave * 8 + r8) * DKK + cg * 8,
                 &Ks[buf][wave * 512]);
    async_copy16(vtb + (size_t)(wave * 8 + r8) * SS + kt * 64 + cg * 8,
                 &Vs[buf][wave * 512]);
  };

  // Prologue: stage first tile, drain, barrier.
  stage(ktBeg, 0);
  __syncthreads();

  int cur = 0;
  for (int kt = ktBeg; kt < ktEnd; kt++) {
    // Issue next tile's loads FIRST -> latency hides under this tile's
    // compute; the single end-of-iteration barrier drains them.
    if (kt + 1 < ktEnd) stage(kt + 1, cur ^ 1);

    if (kt <= myDiag) {
      // ---- swapped QK^T: sc[ct][r] = S[token = kt*64+ct*16+quad*4+r]
      //                                 [qrow  = rbase + col] ----
      f32x4 sc[4] = {};
      __builtin_amdgcn_s_setprio(1);
#pragma unroll
      for (int ct = 0; ct < 4; ct++)
#pragma unroll
        for (int ks = 0; ks < 2; ks++) {
          const bf16x8 kf = *(const bf16x8*)(&Ks[cur][(ct * 16 + col) * 64 +
                                             (((ks * 4 + quad) ^ (col & 7)) * 8)]);
          sc[ct] = __builtin_amdgcn_mfma_f32_16x16x32_bf16(kf, qf[ks], sc[ct],
                                                           0, 0, 0);
        }
      __builtin_amdgcn_s_setprio(0);

      // ---- softmax: p = 2^(s*C1 - C2); packed b64 store to Ps[qrow][token],
      // token = ct*16 + quad*4 + r, qrow = col. Mask only on diag tile. ----
      if (kt < myDiag) {
#pragma unroll
        for (int ct = 0; ct < 4; ct++) {
          float p0 = exp2f(sc[ct][0] * kC1 - kC2);
          float p1 = exp2f(sc[ct][1] * kC1 - kC2);
          float p2 = exp2f(sc[ct][2] * kC1 - kC2);
          float p3 = exp2f(sc[ct][3] * kC1 - kC2);
          l_lane += (p0 + p1) + (p2 + p3);
          bf16x4 pv;
          pv[0] = (__bf16)p0; pv[1] = (__bf16)p1;
          pv[2] = (__bf16)p2; pv[3] = (__bf16)p3;
          *(bf16x4*)(pw + col * 72 + ct * 16 + quad * 4) = pv;
        }
      } else {
        // diag tile: token-local (ct*16+quad*4+r) vs qrow-local (w4*16+col)
#pragma unroll
        for (int ct = 0; ct < 4; ct++) {
          bf16x4 pv;
          if (ct > w4) {  // whole 16-token block above the diagonal
            pv[0] = pv[1] = pv[2] = pv[3] = (__bf16)0.0f;
          } else if (ct < w4) {  // fully below: no mask
            float p0 = exp2f(sc[ct][0] * kC1 - kC2);
            float p1 = exp2f(sc[ct][1] * kC1 - kC2);
            float p2 = exp2f(sc[ct][2] * kC1 - kC2);
            float p3 = exp2f(sc[ct][3] * kC1 - kC2);
            l_lane += (p0 + p1) + (p2 + p3);
            pv[0] = (__bf16)p0; pv[1] = (__bf16)p1;
            pv[2] = (__bf16)p2; pv[3] = (__bf16)p3;
          } else {  // ct == w4: per-element mask
#pragma unroll
            for (int r = 0; r < 4; r++) {
              float p = exp2f(sc[ct][r] * kC1 - kC2);
              if (quad * 4 + r > col) p = 0.0f;
              l_lane += p;
              pv[r] = (__bf16)p;
            }
          }
          *(bf16x4*)(pw + col * 72 + ct * 16 + quad * 4) = pv;
        }
      }

      // ---- PV: O[qrow][dt*16+col] += P @ Vt^T (wave-private P) ----
      {
        bf16x8 pf[2];
#pragma unroll
        for (int ks = 0; ks < 2; ks++)
          pf[ks] = *(const bf16x8*)(pw + col * 72 + ks * 32 + quad * 8);
        __builtin_amdgcn_s_setprio(1);
#pragma unroll
        for (int dt = 0; dt < 4; dt++)
#pragma unroll
          for (int ks = 0; ks < 2; ks++) {
            const bf16x8 vf = *(const bf16x8*)(&Vs[cur][(dt * 16 + col) * 64 +
                                               (((ks * 4 + quad) ^ (col & 7)) * 8)]);
            oacc[dt] = __builtin_amdgcn_mfma_f32_16x16x32_bf16(pf[ks], vf,
                                                               oacc[dt], 0, 0, 0);
          }
        __builtin_amdgcn_s_setprio(0);
      }
    }

    // One barrier per tile: waits this tile's readers AND next tile's
    // prefetch (already overlapped with the compute above).
    __syncthreads();
    cur ^= 1;
  }

  // Reduce l over quads: after these, every lane holds l[qrow = col].
  float l = l_lane;
  l += __shfl_xor(l, 16, 64);
  l += __shfl_xor(l, 32, 64);

  if (!isSplit) {
    // Whole qtile: normalize and write o directly.
#pragma unroll
    for (int r = 0; r < 4; r++) {
      const float lr = __shfl(l, quad * 4 + r, 64);
      const float inv_l = 1.0f / lr;
      const int s = rbase + quad * 4 + r;
#pragma unroll
      for (int dt = 0; dt < 4; dt++)
        o[((size_t)(b * SS + s) * HH + h) * DKK + dt * 16 + col] =
            (__bf16)(oacc[dt][r] * inv_l);
    }
  } else {
    // Split half: dump unnormalized fp32 O + per-row l; combine divides.
    const int tile = (bh * 7 + (qtile - 9)) * 2 + half;
    float* Op = Opart + (size_t)tile * (128 * 64);
#pragma unroll
    for (int r = 0; r < 4; r++) {
      const int row = wave * 16 + quad * 4 + r;
#pragma unroll
      for (int dt = 0; dt < 4; dt++)
        Op[row * 64 + dt * 16 + col] = oacc[dt][r];
    }
    if (quad == 0) lpart[tile * 128 + wave * 16 + col] = l;
  }
}

// ---------------------------------------------------------------------------
// Combine split-KV partials: o = (Oa + Ob) / (la + lb), write bf16.
// grid 224 = 32 bh x 7 qtiles (9..15); 256 threads: 2 threads per row.
// ---------------------------------------------------------------------------
__global__ __launch_bounds__(256) void combine_kernel(
    const float* __restrict__ Opart, const float* __restrict__ lpart,
    __bf16* __restrict__ o) {
  const int bh = blockIdx.x / 7, qi = blockIdx.x % 7;
  const int qtile = qi + 9;
  const int b = bh / HH, h = bh % HH;
  const int t = threadIdx.x;
  const int row = t >> 1, dk0 = (t & 1) * 32;
  const int ta = (bh * 7 + qi) * 2, tb = ta + 1;
  const float la = lpart[ta * 128 + row], lb = lpart[tb * 128 + row];
  const float inv = 1.0f / (la + lb);
  const int s = qtile * 128 + row;
  const float* Oa = Opart + (size_t)ta * 8192 + row * 64 + dk0;
  const float* Ob = Opart + (size_t)tb * 8192 + row * 64 + dk0;
  __bf16* orow = o + ((size_t)(b * SS + s) * HH + h) * DKK + dk0;
#pragma unroll
  for (int i = 0; i < 32; i += 4) {
    const float4 a = *(const float4*)(Oa + i);
    const float4 bb = *(const float4*)(Ob + i);
    orow[i + 0] = (__bf16)((a.x + bb.x) * inv);
    orow[i + 1] = (__bf16)((a.y + bb.y) * inv);
    orow[i + 2] = (__bf16)((a.z + bb.z) * inv);
    orow[i + 3] = (__bf16)((a.w + bb.w) * inv);
  }
}

// ---------------------------------------------------------------------------
extern "C" void kernel_launch(void* const* d_in, const int* in_sizes, int n_in,
                              void* d_out, int out_size, void* d_ws,
                              size_t ws_size, hipStream_t stream) {
  const float* x  = (const float*)d_in[0];
  const int*  pos = (const int*)d_in[1];
  const float* Wq = (const float*)d_in[2];
  const float* bq = (const float*)d_in[3];
  const float* Wk = (const float*)d_in[4];
  const float* bk = (const float*)d_in[5];
  const float* Wv = (const float*)d_in[6];
  const float* bv = (const float*)d_in[7];
  const float* Wo = (const float*)d_in[8];
  const float* bo = (const float*)d_in[9];
  float* out = (float*)d_out;

  char* ws = (char*)d_ws;
  __bf16* xb  = (__bf16*)(ws);                          // 8 MB (dead after qkv)
  __bf16* WqT = (__bf16*)(ws + ((size_t)8  << 20));     // 2 MB each
  __bf16* WkT = (__bf16*)(ws + ((size_t)10 << 20));
  __bf16* WvT = (__bf16*)(ws + ((size_t)12 << 20));
  __bf16* WoT = (__bf16*)(ws + ((size_t)14 << 20));     // live until oproj
  __bf16* qb  = (__bf16*)(ws + ((size_t)16 << 20));     // 8 MB each
  __bf16* kb  = (__bf16*)(ws + ((size_t)24 << 20));
  __bf16* vtb = (__bf16*)(ws + ((size_t)32 << 20));     // V, transposed layout
  __bf16* ob  = (__bf16*)(ws + ((size_t)40 << 20));
  float2* rtab = (float2*)(ws + ((size_t)48 << 20));    // 1 MB; total 49 MB
  // Split-KV partials REUSE memory dead after qkv: Opart over xb/WqT/WkT/WvT
  // (448 tiles x 32 KB = 14 MB = exactly [0,14 MB)); lpart over rtab.
  float* Opart = (float*)(ws);
  float* lpart = (float*)(ws + ((size_t)48 << 20));

  prep_kernel<<<3584, 256, 0, stream>>>(x, pos, Wq, Wk, Wv, Wo, xb, rtab, WqT,
                                        WkT, WvT, WoT);
  qkv_gemm_kernel<<<dim3(24, 32), 256, 0, stream>>>(xb, WqT, WkT, WvT, bq, bk,
                                                    bv, rtab, qb, kb, vtb);
  flash_attn_mfma_kernel<<<dim3(32, 23), 512, 0, stream>>>(qb, kb, vtb, ob,
                                                           Opart, lpart);
  combine_kernel<<<224, 256, 0, stream>>>(Opart, lpart, ob);
  oproj_gemm_kernel<<<dim3(16, 32), 256, 0, stream>>>(ob, WoT, bo, out);
}

// Round 15
// 190.643 us; speedup vs baseline: 1.0290x; 1.0038x over previous
//
#include <hip/hip_runtime.h>
#include <math.h>

// Problem constants
#define BB  2
#define SS  2048
#define DD  1024
#define HH  16
#define DKK 64

constexpr float kScale = 0.125f;  // 1/sqrt(64)
// p = exp(s*kScale - 16) = 2^(s*C1 - C2); exp(-16) cancels in O = sum(p*v)/sum(p)
constexpr float kC1 = 0.18033688011112042f;  // kScale * log2(e)
constexpr float kC2 = 23.0831206542234144f;  // 16 * log2(e)

typedef __bf16 bf16x8 __attribute__((ext_vector_type(8)));
typedef __bf16 bf16x4 __attribute__((ext_vector_type(4)));
typedef float f32x4 __attribute__((ext_vector_type(4)));

// Async global->LDS, 16 B per lane. LDS dest must be WAVE-UNIFORM base;
// HW scatters lane i to base + i*16.
__device__ __forceinline__ void async_copy16(const void* g, void* l) {
  __builtin_amdgcn_global_load_lds(
      (const __attribute__((address_space(1))) void*)g,
      (__attribute__((address_space(3))) void*)l, 16, 0, 0);
}

// ---------------------------------------------------------------------------
// Fused prep: blocks [0,2048) x->bf16 cvt; [2048,2560) RoPE table;
// [2560,3584) weight transpose+cvt (4 mats x 256 tile-blocks).
// ---------------------------------------------------------------------------
__global__ __launch_bounds__(256) void prep_kernel(
    const float* __restrict__ x, const int* __restrict__ pos,
    const float* __restrict__ W0, const float* __restrict__ W1,
    const float* __restrict__ W2, const float* __restrict__ W3,
    __bf16* __restrict__ xb, float2* __restrict__ rtab,
    __bf16* __restrict__ T0, __bf16* __restrict__ T1,
    __bf16* __restrict__ T2, __bf16* __restrict__ T3) {
  __shared__ __bf16 tile[64][65];
  const int bid = blockIdx.x;
  const int t = threadIdx.x;
  if (bid < 2048) {
    const size_t i = ((size_t)bid * 256 + t) * 8;
    const float4 v0 = *(const float4*)(x + i);
    const float4 v1 = *(const float4*)(x + i + 4);
    bf16x8 o;
    o[0] = (__bf16)v0.x; o[1] = (__bf16)v0.y; o[2] = (__bf16)v0.z; o[3] = (__bf16)v0.w;
    o[4] = (__bf16)v1.x; o[5] = (__bf16)v1.y; o[6] = (__bf16)v1.z; o[7] = (__bf16)v1.w;
    *(bf16x8*)(xb + i) = o;
  } else if (bid < 2560) {
    const int idx = (bid - 2048) * 256 + t;  // 131072 = 4096*32
    const int m = idx >> 5, pi = idx & 31;
    const float inv = exp2f(-0.4152410118609203f * (float)pi);
    float sn, cs;
    __sincosf((float)pos[m] * inv, &sn, &cs);
    rtab[idx] = make_float2(cs, sn);
  } else {
    const int tid2 = bid - 2560;
    const int z = tid2 >> 8, rem = tid2 & 255;
    const float* W;
    __bf16* T;
    switch (z) {
      case 0: W = W0; T = T0; break;
      case 1: W = W1; T = T1; break;
      case 2: W = W2; T = T2; break;
      default: W = W3; T = T3; break;
    }
    const int k0 = (rem >> 4) * 64, n0 = (rem & 15) * 64;
    const int c = t & 63, rg = t >> 6;
#pragma unroll
    for (int i = 0; i < 16; i++) {
      const int r = rg + i * 4;
      tile[r][c] = (__bf16)W[(size_t)(k0 + r) * DD + n0 + c];
    }
    __syncthreads();
#pragma unroll
    for (int i = 0; i < 16; i++) {
      const int r = rg + i * 4;
      T[(size_t)(n0 + r) * DD + k0 + c] = tile[c][r];
    }
  }
}

// ---------------------------------------------------------------------------
// R11 GEMM core: BK=32, TRIPLE-BUFFERED LDS (48 KB total, 3 blocks/CU),
// counted s_waitcnt vmcnt(4) + raw s_barrier (NO vmcnt(0) drain in the main
// loop -- T4). Depth-2 pipeline: tile kt's loads issued in iter kt-2,
// waited at top of iter kt. Race-free: every wave's MFMAs consume its
// ds_reads before barrier(k), so after barrier(k) all reads of buf[(k-1)%3]
// are done and stage(k+2) may overwrite it; vmcnt retires in issue order.
// LDS layout per buffer: [128 rows][4 chunks of 8 bf16]; read slot for
// k-chunk q at row r is q ^ ((r>>1)&3) -> 2 lanes/bank (free). Stage pulls
// the inverse-permuted global chunk into the linear lane-scatter slot.
// C[128,128] += A[128,K] @ Bt[128,K]^T  (K = DD = 1024, 32 steps)
// ---------------------------------------------------------------------------
__device__ __forceinline__ void gemm_core(
    const __bf16* __restrict__ A, const __bf16* __restrict__ Bt,
    int bm, int bn, f32x4 (&acc)[4][4], __bf16* As, __bf16* Bs) {
  const int t = threadIdx.x;
  const int lane = t & 63, wave = t >> 6;
  const int col = lane & 15, quad = lane >> 4;
  const int wm = (wave & 1) * 64, wn = (wave >> 1) * 64;

  // Stage-side: lane -> (row offset r16 = lane>>2, slot = lane&3).
  // Global chunk feeding linear slot s at row r: s ^ ((r16>>1)&3).
  const int r16 = lane >> 2;
  const int gch = (lane & 3) ^ ((r16 >> 1) & 3);
  const __bf16* ag = A + (size_t)(bm + wave * 32 + r16) * DD + gch * 8;
  const __bf16* bg = Bt + (size_t)(bn + wave * 32 + r16) * DD + gch * 8;
  __bf16* asb = As + wave * 1024;  // rows wave*32..+31, 32 elems/row
  __bf16* bsb = Bs + wave * 1024;

  // Read-side swizzled chunk: (row>>1)&3 == (col>>1)&3 for our rows.
  const int rch = (quad ^ ((col >> 1) & 3)) * 8;

  auto stage = [&](int kt, int buf) {
    const int bo = buf * 4096;  // 128 rows * 32 elems per buffer
    async_copy16(ag + kt, asb + bo);                          // rows +0..15
    async_copy16(ag + (size_t)16 * DD + kt, asb + bo + 512);  // rows +16..31
    async_copy16(bg + kt, bsb + bo);
    async_copy16(bg + (size_t)16 * DD + kt, bsb + bo + 512);
  };

  // Prologue: issue tiles 0 and 1 (8 loads in flight).
  stage(0, 0);
  stage(32, 1);

  int rb = 0, sb = 2;  // read buffer, stage buffer (rotating mod 3)
#pragma unroll 1
  for (int step = 0; step < 32; step++) {
    // Wait only the OLDEST tile (kt): keep tile kt+1's 4 loads in flight.
    if (step < 31)
      asm volatile("s_waitcnt vmcnt(4)" ::: "memory");
    else
      asm volatile("s_waitcnt vmcnt(0)" ::: "memory");
    __builtin_amdgcn_s_barrier();      // raw barrier: NO vmcnt drain
    asm volatile("" ::: "memory");     // pin ds_reads below the barrier

    const int bo = rb * 4096;
    bf16x8 af[4], bf[4];
#pragma unroll
    for (int i = 0; i < 4; i++)
      af[i] = *(const bf16x8*)(As + bo + (wm + i * 16 + col) * 32 + rch);
#pragma unroll
    for (int j = 0; j < 4; j++)
      bf[j] = *(const bf16x8*)(Bs + bo + (wn + j * 16 + col) * 32 + rch);

    // Issue tile step+2 into the buffer read in iter step-1 (safe: see top).
    if (step + 2 < 32) stage((step + 2) * 32, sb);

    __builtin_amdgcn_s_setprio(1);
#pragma unroll
    for (int i = 0; i < 4; i++)
#pragma unroll
      for (int j = 0; j < 4; j++)
        acc[i][j] =
            __builtin_amdgcn_mfma_f32_16x16x32_bf16(af[i], bf[j], acc[i][j], 0, 0, 0);
    __builtin_amdgcn_s_setprio(0);

    rb = rb == 2 ? 0 : rb + 1;
    sb = sb == 2 ? 0 : sb + 1;
  }
}

// ---------------------------------------------------------------------------
// R18 narrow GEMM core: C[128,64] += A[128,K] @ Bt[64,K]^T. Same R11
// schedule, 64-wide B tile: 3 stage calls/step -> vmcnt(3); wave grid
// 2M x 2N; acc[4][2], 8 MFMA + 6 ds_read/step. LDS 36 KB.
// ---------------------------------------------------------------------------
__device__ __forceinline__ void gemm_core_n64(
    const __bf16* __restrict__ A, const __bf16* __restrict__ Bt,
    int bm, int bn, f32x4 (&acc)[4][2], __bf16* As, __bf16* Bs) {
  const int t = threadIdx.x;
  const int lane = t & 63, wave = t >> 6;
  const int col = lane & 15, quad = lane >> 4;
  const int wm = (wave & 1) * 64, wn = (wave >> 1) * 32;

  const int r16 = lane >> 2;
  const int gch = (lane & 3) ^ ((r16 >> 1) & 3);
  const __bf16* ag = A + (size_t)(bm + wave * 32 + r16) * DD + gch * 8;
  const __bf16* bg = Bt + (size_t)(bn + wave * 16 + r16) * DD + gch * 8;
  __bf16* asb = As + wave * 1024;  // A rows wave*32..+31
  __bf16* bsb = Bs + wave * 512;   // B rows wave*16..+15

  const int rch = (quad ^ ((col >> 1) & 3)) * 8;

  auto stage = [&](int kt, int buf) {
    async_copy16(ag + kt, asb + buf * 4096);
    async_copy16(ag + (size_t)16 * DD + kt, asb + buf * 4096 + 512);
    async_copy16(bg + kt, bsb + buf * 2048);
  };

  stage(0, 0);
  stage(32, 1);

  int rb = 0, sb = 2;
#pragma unroll 1
  for (int step = 0; step < 32; step++) {
    if (step < 31)
      asm volatile("s_waitcnt vmcnt(3)" ::: "memory");
    else
      asm volatile("s_waitcnt vmcnt(0)" ::: "memory");
    __builtin_amdgcn_s_barrier();
    asm volatile("" ::: "memory");

    bf16x8 af[4], bf[2];
#pragma unroll
    for (int i = 0; i < 4; i++)
      af[i] = *(const bf16x8*)(As + rb * 4096 + (wm + i * 16 + col) * 32 + rch);
#pragma unroll
    for (int j = 0; j < 2; j++)
      bf[j] = *(const bf16x8*)(Bs + rb * 2048 + (wn + j * 16 + col) * 32 + rch);

    if (step + 2 < 32) stage((step + 2) * 32, sb);

    __builtin_amdgcn_s_setprio(1);
#pragma unroll
    for (int i = 0; i < 4; i++)
#pragma unroll
      for (int j = 0; j < 2; j++)
        acc[i][j] =
            __builtin_amdgcn_mfma_f32_16x16x32_bf16(af[i], bf[j], acc[i][j], 0, 0, 0);
    __builtin_amdgcn_s_setprio(0);

    rb = rb == 2 ? 0 : rb + 1;
    sb = sb == 2 ? 0 : sb + 1;
  }
}

// ---------------------------------------------------------------------------
// Fused Q/K/V projection. grid (24, 32): blockIdx.x = mat*8 + n-tile.
// Q,K: RoPE via table, scatter [B,H,S,DK].
// V: operand-swapped MFMA (C^T = Wv^T x^T) -> written DIRECTLY in [B,H,DK,S].
// ---------------------------------------------------------------------------
__global__ __launch_bounds__(256, 3) void qkv_gemm_kernel(
    const __bf16* __restrict__ xb, const __bf16* __restrict__ WqT,
    const __bf16* __restrict__ WkT, const __bf16* __restrict__ WvT,
    const float* __restrict__ bq, const float* __restrict__ bk,
    const float* __restrict__ bv, const float2* __restrict__ ropetab,
    __bf16* __restrict__ qo, __bf16* __restrict__ ko, __bf16* __restrict__ vo) {
  __shared__ __bf16 As[3 * 128 * 32];
  __shared__ __bf16 Bs[3 * 128 * 32];
  const int mat = blockIdx.x >> 3;
  const int bn = (blockIdx.x & 7) * 128;
  const int bm = blockIdx.y * 128;

  f32x4 acc[4][4] = {};
  const int t = threadIdx.x, lane = t & 63, wave = t >> 6;
  const int col = lane & 15, quad = lane >> 4;
  const int wm = (wave & 1) * 64, wn = (wave >> 1) * 64;

  if (mat == 2) {
    // A-operand = WvT rows (n-dim), B-operand = xb rows (m-dim)
    gemm_core(WvT, xb, bn, bm, acc, As, Bs);
    // acc[i][j][r] = Vt[n = bn+wm+i*16+quad*4+r][m = bm+wn+j*16+col]
    const int b = bm >> 11;
#pragma unroll
    for (int i = 0; i < 4; i++) {
#pragma unroll
      for (int r = 0; r < 4; r++) {
        const int n = bn + wm + i * 16 + quad * 4 + r;
        const float bb = bv[n];
        const int h = n >> 6, dk = n & 63;
        __bf16* vrow = vo + ((size_t)(b * HH + h) * DKK + dk) * SS;
#pragma unroll
        for (int j = 0; j < 4; j++) {
          const int m = bm + wn + j * 16 + col;
          vrow[m & (SS - 1)] = (__bf16)(acc[i][j][r] + bb);
        }
      }
    }
    return;
  }

  const __bf16* Bt = mat == 0 ? WqT : WkT;
  const float* bias = mat == 0 ? bq : bk;
  __bf16* out = mat == 0 ? qo : ko;
  gemm_core(xb, Bt, bm, bn, acc, As, Bs);

#pragma unroll
  for (int i = 0; i < 4; i++) {
#pragma unroll
    for (int j = 0; j < 4; j++) {
      const int n = bn + wn + j * 16 + col;
      const float bb = bias[n];
      const int pi = (n & 63) >> 1;
#pragma unroll
      for (int r = 0; r < 4; r++) {
        const int m = bm + wm + i * 16 + quad * 4 + r;
        float v = acc[i][j][r] + bb;
        {
          const float other = __shfl_xor(v, 1, 64);
          const float2 cssn = ropetab[(size_t)m * 32 + pi];
          v = (n & 1) ? (other * cssn.y + v * cssn.x)
                      : (v * cssn.x - other * cssn.y);
        }
        const int h = n >> 6, dk = n & 63;
        const int b = m >> 11, s = m & (SS - 1);
        out[((size_t)(b * HH + h) * SS + s) * DKK + dk] = (__bf16)v;
      }
    }
  }
}

// ---------------------------------------------------------------------------
// O projection: 128x64 tiles, grid (16, 32) = 512 blocks = 2/CU.
// out[M,N] fp32 = ob[M,K] @ WoT[N,K]^T + bo.
// ---------------------------------------------------------------------------
__global__ __launch_bounds__(256, 4) void oproj_gemm_kernel(
    const __bf16* __restrict__ ob, const __bf16* __restrict__ WoT,
    const float* __restrict__ bo, float* __restrict__ out) {
  __shared__ __bf16 As[3 * 128 * 32];
  __shared__ __bf16 Bs[3 * 64 * 32];
  const int bn = blockIdx.x * 64;
  const int bm = blockIdx.y * 128;
  f32x4 acc[4][2] = {};
  gemm_core_n64(ob, WoT, bm, bn, acc, As, Bs);

  const int t = threadIdx.x, lane = t & 63, wave = t >> 6;
  const int col = lane & 15, quad = lane >> 4;
  const int wm = (wave & 1) * 64, wn = (wave >> 1) * 32;
#pragma unroll
  for (int i = 0; i < 4; i++) {
#pragma unroll
    for (int j = 0; j < 2; j++) {
      const int n = bn + wn + j * 16 + col;
      const float bb = bo[n];
#pragma unroll
      for (int r = 0; r < 4; r++) {
        const int m = bm + wm + i * 16 + quad * 4 + r;
        out[(size_t)m * DD + n] = acc[i][j][r] + bb;
      }
    }
  }
}

// ---------------------------------------------------------------------------
// MFMA flash attention (R12 body; R20 change: launch_bounds (512,6)->(512,3).
// (512,6) requested an impossible 6 blocks/CU (3072 thr > 2048) and the
// allocator clamped VGPR to ~42 (observed 40). Occupancy is LDS-capped at
// 3 blocks/CU (50 KB) regardless, so the tight cap bought nothing; (512,3)
// matches the real occupancy and raises the VGPR budget to ~85, giving the
// scheduler headroom (exp-chain pipelining, fewer LDS re-reads). Bodies
// byte-identical; worst case neutral.
// Split-KV: 8-wave 512-thread blocks, 128-row Q-supertile, grid (32,23) =
// 736 blocks co-resident at 3 blocks/CU.
//   y in [0,14): split halves of qtiles 9..15; y in [14,23): whole 8..0.
// Refuted by counters: reg-P (R13/14), fused-combine fences (R9), 32x32
// MFMA (R16), nSplit=8 (R13). Fixed-max softmax => partials ADDITIVE:
// split halves write unnormalized fp32 O + per-row l; combine divides.
// p = 2^(s*C1-C2). q,k in [B,H,S,DK]; vt in [B,H,DK,S]; o [B,S,H,DK] bf16.
// ---------------------------------------------------------------------------
__global__ __launch_bounds__(512, 3) void flash_attn_mfma_kernel(
    const __bf16* __restrict__ q, const __bf16* __restrict__ k,
    const __bf16* __restrict__ vt, __bf16* __restrict__ o,
    float* __restrict__ Opart, float* __restrict__ lpart) {
  __shared__ __bf16 Ks[2][64 * 64];    // [buf][j][dk], chunk-swizzled
  __shared__ __bf16 Vs[2][64 * 64];    // [buf][d][j],  chunk-swizzled
  __shared__ __bf16 Ps[8][16 * 72];    // per-wave [qrow][j], stride 72

  const int bh = blockIdx.x;            // 0..31
  const int y = blockIdx.y;             // 0..22
  int qtile, ktBeg, ktEnd, half;
  bool isSplit;
  if (y < 14) {
    qtile = 15 - (y >> 1);
    half = y & 1;
    isSplit = true;
    ktBeg = half ? (qtile + 1) : 0;
    ktEnd = half ? (2 * qtile + 2) : (qtile + 1);
  } else {
    qtile = 22 - y;                     // 8..0
    half = 0;
    isSplit = false;
    ktBeg = 0;
    ktEnd = 2 * qtile + 2;
  }

  const int t = threadIdx.x, lane = t & 63, wave = t >> 6;  // wave 0..7
  const int col = lane & 15, quad = lane >> 4;
  const int r8 = lane >> 3;             // row in 8-row slab
  const int cg = (lane & 7) ^ r8;       // swizzled global chunk
  const int w4 = wave & 3;              // 16-row group within 64-row half

  const __bf16* qb = q + (size_t)bh * SS * DKK;
  const __bf16* kb = k + (size_t)bh * SS * DKK;
  const __bf16* vtb = vt + (size_t)bh * DKK * SS;
  const int b = bh / HH, h = bh % HH;
  __bf16* pw = (__bf16*)Ps[wave];

  const int rbase = qtile * 128 + wave * 16;  // this wave's 16 q-rows
  const int myDiag = 2 * qtile + (wave >> 2); // K-tile straddling my rows

  // Q fragments held in registers (B-operand of swapped QK^T: lane col holds
  // q-row rbase+col, k-elems ks*32+quad*8..+7)
  bf16x8 qf[2];
#pragma unroll
  for (int ks = 0; ks < 2; ks++)
    qf[ks] = *(const bf16x8*)(qb + (size_t)(rbase + col) * DKK + ks * 32 +
                              quad * 8);

  f32x4 oacc[4] = {};
  float l_lane = 0.f;

  // Stage K/V tile kt into buffer buf; wave w covers slab w (8 rows each).
  auto stage = [&](int kt, int buf) {
    async_copy16(kb + (size_t)(kt * 64 + wave * 8 + r8) * DKK + cg * 8,
                 &Ks[buf][wave * 512]);
    async_copy16(vtb + (size_t)(wave * 8 + r8) * SS + kt * 64 + cg * 8,
                 &Vs[buf][wave * 512]);
  };

  // Prologue: stage first tile, drain, barrier.
  stage(ktBeg, 0);
  __syncthreads();

  int cur = 0;
  for (int kt = ktBeg; kt < ktEnd; kt++) {
    // Issue next tile's loads FIRST -> latency hides under this tile's
    // compute; the single end-of-iteration barrier drains them.
    if (kt + 1 < ktEnd) stage(kt + 1, cur ^ 1);

    if (kt <= myDiag) {
      // ---- swapped QK^T: sc[ct][r] = S[token = kt*64+ct*16+quad*4+r]
      //                                 [qrow  = rbase + col] ----
      f32x4 sc[4] = {};
      __builtin_amdgcn_s_setprio(1);
#pragma unroll
      for (int ct = 0; ct < 4; ct++)
#pragma unroll
        for (int ks = 0; ks < 2; ks++) {
          const bf16x8 kf = *(const bf16x8*)(&Ks[cur][(ct * 16 + col) * 64 +
                                             (((ks * 4 + quad) ^ (col & 7)) * 8)]);
          sc[ct] = __builtin_amdgcn_mfma_f32_16x16x32_bf16(kf, qf[ks], sc[ct],
                                                           0, 0, 0);
        }
      __builtin_amdgcn_s_setprio(0);

      // ---- softmax: p = 2^(s*C1 - C2); packed b64 store to Ps[qrow][token],
      // token = ct*16 + quad*4 + r, qrow = col. Mask only on diag tile. ----
      if (kt < myDiag) {
#pragma unroll
        for (int ct = 0; ct < 4; ct++) {
          float p0 = exp2f(sc[ct][0] * kC1 - kC2);
          float p1 = exp2f(sc[ct][1] * kC1 - kC2);
          float p2 = exp2f(sc[ct][2] * kC1 - kC2);
          float p3 = exp2f(sc[ct][3] * kC1 - kC2);
          l_lane += (p0 + p1) + (p2 + p3);
          bf16x4 pv;
          pv[0] = (__bf16)p0; pv[1] = (__bf16)p1;
          pv[2] = (__bf16)p2; pv[3] = (__bf16)p3;
          *(bf16x4*)(pw + col * 72 + ct * 16 + quad * 4) = pv;
        }
      } else {
        // diag tile: token-local (ct*16+quad*4+r) vs qrow-local (w4*16+col)
#pragma unroll
        for (int ct = 0; ct < 4; ct++) {
          bf16x4 pv;
          if (ct > w4) {  // whole 16-token block above the diagonal
            pv[0] = pv[1] = pv[2] = pv[3] = (__bf16)0.0f;
          } else if (ct < w4) {  // fully below: no mask
            float p0 = exp2f(sc[ct][0] * kC1 - kC2);
            float p1 = exp2f(sc[ct][1] * kC1 - kC2);
            float p2 = exp2f(sc[ct][2] * kC1 - kC2);
            float p3 = exp2f(sc[ct][3] * kC1 - kC2);
            l_lane += (p0 + p1) + (p2 + p3);
            pv[0] = (__bf16)p0; pv[1] = (__bf16)p1;
            pv[2] = (__bf16)p2; pv[3] = (__bf16)p3;
          } else {  // ct == w4: per-element mask
#pragma unroll
            for (int r = 0; r < 4; r++) {
              float p = exp2f(sc[ct][r] * kC1 - kC2);
              if (quad * 4 + r > col) p = 0.0f;
              l_lane += p;
              pv[r] = (__bf16)p;
            }
          }
          *(bf16x4*)(pw + col * 72 + ct * 16 + quad * 4) = pv;
        }
      }

      // ---- PV: O[qrow][dt*16+col] += P @ Vt^T (wave-private P) ----
      {
        bf16x8 pf[2];
#pragma unroll
        for (int ks = 0; ks < 2; ks++)
          pf[ks] = *(const bf16x8*)(pw + col * 72 + ks * 32 + quad * 8);
        __builtin_amdgcn_s_setprio(1);
#pragma unroll
        for (int dt = 0; dt < 4; dt++)
#pragma unroll
          for (int ks = 0; ks < 2; ks++) {
            const bf16x8 vf = *(const bf16x8*)(&Vs[cur][(dt * 16 + col) * 64 +
                                               (((ks * 4 + quad) ^ (col & 7)) * 8)]);
            oacc[dt] = __builtin_amdgcn_mfma_f32_16x16x32_bf16(pf[ks], vf,
                                                               oacc[dt], 0, 0, 0);
          }
        __builtin_amdgcn_s_setprio(0);
      }
    }

    // One barrier per tile: waits this tile's readers AND next tile's
    // prefetch (already overlapped with the compute above).
    __syncthreads();
    cur ^= 1;
  }

  // Reduce l over quads: after these, every lane holds l[qrow = col].
  float l = l_lane;
  l += __shfl_xor(l, 16, 64);
  l += __shfl_xor(l, 32, 64);

  if (!isSplit) {
    // Whole qtile: normalize and write o directly.
#pragma unroll
    for (int r = 0; r < 4; r++) {
      const float lr = __shfl(l, quad * 4 + r, 64);
      const float inv_l = 1.0f / lr;
      const int s = rbase + quad * 4 + r;
#pragma unroll
      for (int dt = 0; dt < 4; dt++)
        o[((size_t)(b * SS + s) * HH + h) * DKK + dt * 16 + col] =
            (__bf16)(oacc[dt][r] * inv_l);
    }
  } else {
    // Split half: dump unnormalized fp32 O + per-row l; combine divides.
    const int tile = (bh * 7 + (qtile - 9)) * 2 + half;
    float* Op = Opart + (size_t)tile * (128 * 64);
#pragma unroll
    for (int r = 0; r < 4; r++) {
      const int row = wave * 16 + quad * 4 + r;
#pragma unroll
      for (int dt = 0; dt < 4; dt++)
        Op[row * 64 + dt * 16 + col] = oacc[dt][r];
    }
    if (quad == 0) lpart[tile * 128 + wave * 16 + col] = l;
  }
}

// ---------------------------------------------------------------------------
// Combine split-KV partials: o = (Oa + Ob) / (la + lb), write bf16.
// grid 224 = 32 bh x 7 qtiles (9..15); 256 threads: 2 threads per row.
// ---------------------------------------------------------------------------
__global__ __launch_bounds__(256) void combine_kernel(
    const float* __restrict__ Opart, const float* __restrict__ lpart,
    __bf16* __restrict__ o) {
  const int bh = blockIdx.x / 7, qi = blockIdx.x % 7;
  const int qtile = qi + 9;
  const int b = bh / HH, h = bh % HH;
  const int t = threadIdx.x;
  const int row = t >> 1, dk0 = (t & 1) * 32;
  const int ta = (bh * 7 + qi) * 2, tb = ta + 1;
  const float la = lpart[ta * 128 + row], lb = lpart[tb * 128 + row];
  const float inv = 1.0f / (la + lb);
  const int s = qtile * 128 + row;
  const float* Oa = Opart + (size_t)ta * 8192 + row * 64 + dk0;
  const float* Ob = Opart + (size_t)tb * 8192 + row * 64 + dk0;
  __bf16* orow = o + ((size_t)(b * SS + s) * HH + h) * DKK + dk0;
#pragma unroll
  for (int i = 0; i < 32; i += 4) {
    const float4 a = *(const float4*)(Oa + i);
    const float4 bb = *(const float4*)(Ob + i);
    orow[i + 0] = (__bf16)((a.x + bb.x) * inv);
    orow[i + 1] = (__bf16)((a.y + bb.y) * inv);
    orow[i + 2] = (__bf16)((a.z + bb.z) * inv);
    orow[i + 3] = (__bf16)((a.w + bb.w) * inv);
  }
}

// ---------------------------------------------------------------------------
extern "C" void kernel_launch(void* const* d_in, const int* in_sizes, int n_in,
                              void* d_out, int out_size, void* d_ws,
                              size_t ws_size, hipStream_t stream) {
  const float* x  = (const float*)d_in[0];
  const int*  pos = (const int*)d_in[1];
  const float* Wq = (const float*)d_in[2];
  const float* bq = (const float*)d_in[3];
  const float* Wk = (const float*)d_in[4];
  const float* bk = (const float*)d_in[5];
  const float* Wv = (const float*)d_in[6];
  const float* bv = (const float*)d_in[7];
  const float* Wo = (const float*)d_in[8];
  const float* bo = (const float*)d_in[9];
  float* out = (float*)d_out;

  char* ws = (char*)d_ws;
  __bf16* xb  = (__bf16*)(ws);                          // 8 MB (dead after qkv)
  __bf16* WqT = (__bf16*)(ws + ((size_t)8  << 20));     // 2 MB each
  __bf16* WkT = (__bf16*)(ws + ((size_t)10 << 20));
  __bf16* WvT = (__bf16*)(ws + ((size_t)12 << 20));
  __bf16* WoT = (__bf16*)(ws + ((size_t)14 << 20));     // live until oproj
  __bf16* qb  = (__bf16*)(ws + ((size_t)16 << 20));     // 8 MB each
  __bf16* kb  = (__bf16*)(ws + ((size_t)24 << 20));
  __bf16* vtb = (__bf16*)(ws + ((size_t)32 << 20));     // V, transposed layout
  __bf16* ob  = (__bf16*)(ws + ((size_t)40 << 20));
  float2* rtab = (float2*)(ws + ((size_t)48 << 20));    // 1 MB; total 49 MB
  // Split-KV partials REUSE memory dead after qkv: Opart over xb/WqT/WkT/WvT
  // (448 tiles x 32 KB = 14 MB = exactly [0,14 MB)); lpart over rtab.
  float* Opart = (float*)(ws);
  float* lpart = (float*)(ws + ((size_t)48 << 20));

  prep_kernel<<<3584, 256, 0, stream>>>(x, pos, Wq, Wk, Wv, Wo, xb, rtab, WqT,
                                        WkT, WvT, WoT);
  qkv_gemm_kernel<<<dim3(24, 32), 256, 0, stream>>>(xb, WqT, WkT, WvT, bq, bk,
                                                    bv, rtab, qb, kb, vtb);
  flash_attn_mfma_kernel<<<dim3(32, 23), 512, 0, stream>>>(qb, kb, vtb, ob,
                                                           Opart, lpart);
  combine_kernel<<<224, 256, 0, stream>>>(Opart, lpart, ob);
  oproj_gemm_kernel<<<dim3(16, 32), 256, 0, stream>>>(ob, WoT, bo, out);
}